// Round 20
// baseline (997.760 us; speedup 1.0000x reference)
//
#include <hip/hip_runtime.h>
#include <math.h>

#define NR 8192
#define NPICK 4096
#define SDF_THR_C 5e-5f

// output layout (floats)
#define OUT_DPRED 0
#define OUT_SDFL  8192
#define OUT_SAMP  16384
#define OUT_FIN   139264   // 16384 + 40960*3

typedef __attribute__((ext_vector_type(8))) short short8v;
typedef __attribute__((ext_vector_type(4))) float f32x4;

#define SK  320   // activation plane k-stride (shorts)
#define SKB 640   // bytes per plane row

struct Wptrs { const float* w[8]; };
struct EvalP {
  const float* b[8];
  const float* b8;
  const unsigned short* WTi;   // interleaved: [col][k-chunk(8)][hi 8s | lo 8s]
  const float* w8c;
};

__device__ __forceinline__ unsigned short f2bf(float f) {
  unsigned int u = __float_as_uint(f);
  unsigned int r = u + 0x7FFFu + ((u >> 16) & 1u);
  return (unsigned short)(r >> 16);
}
__device__ __forceinline__ float bf2f(unsigned short h) {
  return __uint_as_float(((unsigned int)h) << 16);
}
// Fast softplus (validated round 9, absmax 0.0156). Embed trig stays EXACT
// sinf/cosf (the risky part of the round-4 failure).
__device__ __forceinline__ float softplus100(float h) {
  float z = 100.0f * h;
  return (fmaxf(z, 0.0f) + __logf(1.0f + __expf(-fabsf(z)))) * 0.01f;
}

// ---------------------------------------------------------------------------
// prep: transpose + bf16 hi/lo split, INTERLEAVED layout (r13)
// ---------------------------------------------------------------------------
__global__ void prep_transpose(Wptrs wp, unsigned short* __restrict__ WTi)
{
  __shared__ unsigned short sh[64 * 66];
  __shared__ unsigned short sl[64 * 66];
  const int Kreal[8] = {39,256,256,256,295,256,256,256};
  const int Kp[8]    = {64,256,256,256,320,256,256,256};
  const int WB[8]    = {0,16384,81920,147456,212992,294912,360448,425984};
  const int cum[9]   = {0,4,20,36,52,72,88,104,120};
  int b = blockIdx.x;
  int l = 0;
  while (l < 7 && b >= cum[l + 1]) ++l;
  int tile = b - cum[l];
  int tk_n = Kp[l] >> 6;
  int tk = tile % tk_n, tc = tile / tk_n;
  const float* __restrict__ W = wp.w[l];
  int t = threadIdx.x;
  #pragma unroll
  for (int i = 0; i < 16; ++i) {
    int id = t + i * 256;
    int kl = id >> 6, cl = id & 63;
    int k = tk * 64 + kl, c = tc * 64 + cl;
    float v = (k < Kreal[l]) ? W[k * 256 + c] : 0.0f;
    unsigned short h = f2bf(v);
    unsigned short lo = f2bf(v - bf2f(h));
    sh[kl * 66 + cl] = h;
    sl[kl * 66 + cl] = lo;
  }
  __syncthreads();
  #pragma unroll
  for (int i = 0; i < 16; ++i) {
    int id = t + i * 256;
    int cl = id >> 6, kl = id & 63;
    int col = tc * 64 + cl;
    int k = tk * 64 + kl;
    size_t base = 2 * ((size_t)WB[l] + (size_t)col * Kp[l] + (k & ~7)) + (k & 7);
    WTi[base]     = sh[kl * 66 + cl];
    WTi[base + 8] = sl[kl * 66 + cl];
  }
}

__global__ void prep_w8(const float* __restrict__ w8, float* __restrict__ w8c)
{
  int t = threadIdx.x;
  w8c[t] = w8[(size_t)t * 257];   // column 0 of (256,257)
}

// ---------------------------------------------------------------------------
// Fused 9-layer MLP via bf16x3 MFMA. pts (M x 3) -> sdf (M).
// 32 rows/block, 1024 threads (16 waves x 16 cols x 2 row-tiles, acc[2]),
// grid 512 -> 2 blocks/CU = 8 waves/SIMD (the TLP ladder's next doubling;
// 1->2->4 waves each won). (1024,8) pins VGPR<=64 (r17's lean loop measured
// 52 — fits). LDS 47 KB/block -> 2 blocks = 94 KB < 160 KB.
// Per-(row,col) MFMA chain identical to r9..r19 -> bit-identical outputs.
// ---------------------------------------------------------------------------
__global__ __launch_bounds__(1024, 8)
void eval_mfma(const float* __restrict__ pts, float* __restrict__ sdf_out, EvalP P)
{
  __shared__ __align__(16) unsigned short Ah[32 * SK];   // 20 KB
  __shared__ __align__(16) unsigned short Al[32 * SK];   // 20 KB
  __shared__ float enc[32 * 40];                         // 5 KB
  __shared__ float red[8 * 32];                          // 1 KB
  const int KpA[8] = {64,256,256,256,320,256,256,256};
  const int WBA[8] = {0,16384,81920,147456,212992,294912,360448,425984};

  const int t = threadIdx.x;
  const int rbase = blockIdx.x * 32;

  // ---- embed: one thread per row -> enc[row][0..38] (EXACT sinf/cosf)
  if (t < 32) {
    const int r = rbase + t;
    float x = pts[3*r+0], y = pts[3*r+1], z = pts[3*r+2];
    float xn = ((x + 1.0f) * 0.5f) * 2.0f - 1.0f;
    float yn = ((y + 1.0f) * 0.5f) * 2.0f - 1.0f;
    float zn = ((z + 1.0f) * 0.5f) * 2.0f - 1.0f;
    float* row = enc + t * 40;
    row[0] = xn; row[1] = yn; row[2] = zn;
    float f = 1.0f;
    for (int lf = 0; lf < 6; ++lf) {
      float ax = xn * f, ay = yn * f, az = zn * f;
      row[3  + lf*3 + 0] = sinf(ax);
      row[3  + lf*3 + 1] = sinf(ay);
      row[3  + lf*3 + 2] = sinf(az);
      row[21 + lf*3 + 0] = cosf(ax);
      row[21 + lf*3 + 1] = cosf(ay);
      row[21 + lf*3 + 2] = cosf(az);
      f *= 2.0f;
    }
  }
  __syncthreads();

  // ---- scatter enc (bf16 hi/lo) to planes: k in [0,64) for L0, [256,320) for L4
  {
    char* ahp = (char*)Ah;
    char* alp = (char*)Al;
    int row = t >> 5, c2 = t & 31;   // 32 rows x 32 chunks of 2 k
    int sw = (row & 7) << 4;
    #pragma unroll
    for (int reg = 0; reg < 2; ++reg) {
      int koff = reg ? 256 : 0;
      int kl = c2 * 2;
      float v0 = (kl     < 39) ? enc[row * 40 + kl]     : 0.0f;
      float v1 = (kl + 1 < 39) ? enc[row * 40 + kl + 1] : 0.0f;
      unsigned short h0 = f2bf(v0), h1 = f2bf(v1);
      unsigned short q0 = f2bf(v0 - bf2f(h0)), q1 = f2bf(v1 - bf2f(h1));
      int addr = row * SKB + (((koff + kl) * 2) ^ sw);
      *(unsigned int*)(ahp + addr) = (unsigned)h0 | ((unsigned)h1 << 16);
      *(unsigned int*)(alp + addr) = (unsigned)q0 | ((unsigned)q1 << 16);
    }
  }
  __syncthreads();

  const int lane = t & 63, wv = t >> 6;   // 16 waves
  const int lq = lane >> 4, lr = lane & 15;
  const int cw = wv * 16;                 // wave owns 16 cols
  const char* ahc = (const char*)Ah;
  const char* alc = (const char*)Al;
  char* ahw = (char*)Ah;
  char* alw = (char*)Al;
  const int swA = (lr & 7) << 4;

  for (int l = 0; l < 8; ++l) {
    const int KpL = KpA[l];
    const int nks = KpL >> 5;
    const unsigned short* __restrict__ wt = P.WTi + 2 * (size_t)WBA[l];
    const int col = cw + lr;
    const unsigned short* wcol = wt + 2 * ((size_t)col * KpL + lq * 8);

    f32x4 acc[2];
    acc[0] = (f32x4){0.f, 0.f, 0.f, 0.f};
    acc[1] = (f32x4){0.f, 0.f, 0.f, 0.f};

    #pragma unroll 2
    for (int ks = 0; ks < nks; ++ks) {
      int ax = (ks * 64 + lq * 16) ^ swA;
      short8v ah0 = *(const short8v*)(ahc + lr * SKB + ax);
      short8v ah1 = *(const short8v*)(ahc + (16 + lr) * SKB + ax);
      short8v al0 = *(const short8v*)(alc + lr * SKB + ax);
      short8v al1 = *(const short8v*)(alc + (16 + lr) * SKB + ax);
      const unsigned short* wb = wcol + 2 * (ks * 32);
      short8v bhv = *(const short8v*)(wb);
      short8v blv = *(const short8v*)(wb + 8);
      acc[0] = __builtin_amdgcn_mfma_f32_16x16x32_bf16(ah0, bhv, acc[0], 0, 0, 0);
      acc[0] = __builtin_amdgcn_mfma_f32_16x16x32_bf16(al0, bhv, acc[0], 0, 0, 0);
      acc[0] = __builtin_amdgcn_mfma_f32_16x16x32_bf16(ah0, blv, acc[0], 0, 0, 0);
      acc[1] = __builtin_amdgcn_mfma_f32_16x16x32_bf16(ah1, bhv, acc[1], 0, 0, 0);
      acc[1] = __builtin_amdgcn_mfma_f32_16x16x32_bf16(al1, bhv, acc[1], 0, 0, 0);
      acc[1] = __builtin_amdgcn_mfma_f32_16x16x32_bf16(ah1, blv, acc[1], 0, 0, 0);
    }

    __syncthreads();   // all plane reads of this layer complete

    {
      float bv = P.b[l][col];
      int cb2 = col * 2;
      #pragma unroll
      for (int rt = 0; rt < 2; ++rt) {
        #pragma unroll
        for (int r = 0; r < 4; ++r) {
          float h = softplus100(acc[rt][r] + bv);
          unsigned short hh = f2bf(h);
          unsigned short hl = f2bf(h - bf2f(hh));
          int row = rt * 16 + lq * 4 + r;
          int addr = row * SKB + (cb2 ^ ((row & 7) << 4));
          *(unsigned short*)(ahw + addr) = hh;
          *(unsigned short*)(alw + addr) = hl;
        }
      }
    }
    __syncthreads();
  }

  // ---- layer 8: column 0 only; same 8x32-k partition + reduce order as r9.
  // threads 0-255: row = t&31, part = t>>5 (8 parts x 32 k, identical grouping).
  {
    if (t < 256) {
      int row = t & 31, part = t >> 5;
      int sw = (row & 7) << 4;
      float s = 0.0f;
      #pragma unroll
      for (int c = 0; c < 4; ++c) {
        int k = part * 32 + c * 8;
        int addr = row * SKB + ((k * 2) ^ sw);
        short8v vh = *(const short8v*)(ahc + addr);
        short8v vl = *(const short8v*)(alc + addr);
        #pragma unroll
        for (int e = 0; e < 8; ++e) {
          float h = bf2f((unsigned short)vh[e]) + bf2f((unsigned short)vl[e]);
          s = fmaf(h, P.w8c[k + e], s);
        }
      }
      red[part * 32 + row] = s;
    }
    __syncthreads();
    if (t < 32) {
      float tot = P.b8[0];
      #pragma unroll
      for (int p = 0; p < 8; ++p) tot += red[p * 32 + t];
      sdf_out[rbase + t] = tot;
    }
  }
}

// ---------------------------------------------------------------------------
// init: ray-AABB, initial points
// ---------------------------------------------------------------------------
__global__ void init_kernel(const float* __restrict__ ray0, const float* __restrict__ rdir,
                            float* tminA, float* tmaxA, float* evalpts, float* ptrack)
{
  int r = blockIdx.x * 256 + threadIdx.x;
  if (r >= NR) return;
  float ox = ray0[3*r], oy = ray0[3*r+1], oz = ray0[3*r+2];
  float dx = rdir[3*r], dy = rdir[3*r+1], dz = rdir[3*r+2];
  float ix = 1.0f/dx, iy = 1.0f/dy, iz = 1.0f/dz;
  float t1x = (-1.0f - ox)*ix, t2x = (1.0f - ox)*ix;
  float t1y = (-1.0f - oy)*iy, t2y = (1.0f - oy)*iy;
  float t1z = (-1.0f - oz)*iz, t2z = (1.0f - oz)*iz;
  float tmn = fmaxf(fmaxf(fminf(t1x,t2x), fminf(t1y,t2y)), fminf(t1z,t2z));
  float tmx = fminf(fminf(fmaxf(t1x,t2x), fmaxf(t1y,t2y)), fmaxf(t1z,t2z));
  tmn = fmaxf(tmn, 0.0f);
  tminA[r] = tmn; tmaxA[r] = tmx;
  float px = ox + tmn*dx, py = oy + tmn*dy, pz = oz + tmn*dz;
  float qx = ox + tmx*dx, qy = oy + tmx*dy, qz = oz + tmx*dz;
  evalpts[3*r+0] = px; evalpts[3*r+1] = py; evalpts[3*r+2] = pz;
  evalpts[3*(NR+r)+0] = qx; evalpts[3*(NR+r)+1] = qy; evalpts[3*(NR+r)+2] = qz;
  ptrack[r*24+0] = px; ptrack[r*24+1] = py; ptrack[r*24+2] = pz;
}

// ---------------------------------------------------------------------------
// march step t
// ---------------------------------------------------------------------------
__global__ void march_kernel(const float* __restrict__ ray0, const float* __restrict__ rdir,
                             const float* __restrict__ raw,
                             float* next_s, float* next_e,
                             int* msel_s, int* msel_e, int* mcar_s, int* mcar_e,
                             float* accS, float* accE,
                             const float* __restrict__ tminA, const float* __restrict__ tmaxA,
                             float* strack, float* ptrack, float* evalpts, int tstep)
{
  int r = blockIdx.x * 256 + threadIdx.x;
  if (r >= NR) return;
  float tmn = tminA[r], tmx = tmaxA[r];
  float rs = raw[r], re = raw[NR + r];
  float ns, ne, as_, ae; int ms, me;
  if (tstep == 0) {
    ns = rs; ne = re; ms = 1; me = 1; as_ = tmn; ae = tmx;
    strack[r*8 + 0] = rs;
  } else {
    ns = next_s[r]; ne = next_e[r];
    ns = msel_s[r] ? rs : ns;        // selection deferred from end of step t-1
    ne = msel_e[r] ? re : ne;
    strack[r*8 + tstep] = rs;        // sdf_tracks[:, t] = unmasked s-eval
    ms = mcar_s[r]; me = mcar_e[r];
    as_ = accS[r]; ae = accE[r];
  }
  float cs = (fabsf(ns) <= SDF_THR_C) ? 0.0f : ns;
  float ce = (fabsf(ne) <= SDF_THR_C) ? 0.0f : ne;
  ms = ms & ((fabsf(cs) > SDF_THR_C) ? 1 : 0);
  me = me & ((fabsf(ce) > SDF_THR_C) ? 1 : 0);
  as_ = fminf(as_ + cs, tmx);
  ae  = fminf(ae + ce, tmx);
  if (tstep < 7) {
    float ox = ray0[3*r], oy = ray0[3*r+1], oz = ray0[3*r+2];
    float dx = rdir[3*r], dy = rdir[3*r+1], dz = rdir[3*r+2];
    float px = ox + as_*dx, py = oy + as_*dy, pz = oz + as_*dz;
    float qx = ox + ae*dx,  qy = oy + ae*dy,  qz = oz + ae*dz;
    ptrack[r*24 + (tstep+1)*3 + 0] = px;
    ptrack[r*24 + (tstep+1)*3 + 1] = py;
    ptrack[r*24 + (tstep+1)*3 + 2] = pz;
    evalpts[3*r+0] = px; evalpts[3*r+1] = py; evalpts[3*r+2] = pz;
    evalpts[3*(NR+r)+0] = qx; evalpts[3*(NR+r)+1] = qy; evalpts[3*(NR+r)+2] = qz;
  }
  int ok = (as_ < ae) ? 1 : 0;
  msel_s[r] = ms;       msel_e[r] = me;        // pre-ok masks: used for next select
  mcar_s[r] = ms & ok;  mcar_e[r] = me & ok;   // carry masks
  next_s[r] = ns; next_e[r] = ne;
  accS[r] = as_; accE[r] = ae;
}

// ---------------------------------------------------------------------------
// finalize: outputs
// ---------------------------------------------------------------------------
__global__ void finalize_kernel(const float* __restrict__ ray0, const float* __restrict__ rdir,
                                const float* __restrict__ frand, const int* __restrict__ pick,
                                const float* __restrict__ strack, const float* __restrict__ ptrack,
                                const float* __restrict__ accE,
                                const float* __restrict__ tminA, const float* __restrict__ tmaxA,
                                float* __restrict__ out)
{
  int r = blockIdx.x * 256 + threadIdx.x;
  if (r < NR) {
    float tmn = tminA[r], tmx = tmaxA[r];
    float sum = 0.f;
    #pragma unroll
    for (int tt = 0; tt < 8; ++tt) sum += strack[r*8 + tt];
    out[OUT_DPRED + r] = fminf(sum + tmn, tmx);
    float last = strack[r*8 + 7];
    out[OUT_SDFL + r] = last;
    out[OUT_FIN + r] = (fabsf(last) < 0.0015625f) ? 1.0f : 0.0f;
    float du = fminf(1.5f * accE[r], tmx);
    float fr = frand[r];
    float dsm = (1.0f - fr) * du + fr * tmn;
    float ox = ray0[3*r], oy = ray0[3*r+1], oz = ray0[3*r+2];
    float dx = rdir[3*r], dy = rdir[3*r+1], dz = rdir[3*r+2];
    int o2 = OUT_SAMP + 98304 + 3*r;
    out[o2+0] = ox + dsm*dx;
    out[o2+1] = oy + dsm*dy;
    out[o2+2] = oz + dsm*dz;
  }
  if (r < NPICK) {
    int ray = pick[r];
    #pragma unroll
    for (int i = 0; i < 24; ++i)
      out[OUT_SAMP + r*24 + i] = ptrack[ray*24 + i];
  }
}

// ---------------------------------------------------------------------------
extern "C" void kernel_launch(void* const* d_in, const int* in_sizes, int n_in,
                              void* d_out, int out_size, void* d_ws, size_t ws_size,
                              hipStream_t stream)
{
  const float* ray0  = (const float*)d_in[0];
  const float* rdir  = (const float*)d_in[1];
  const float* frand = (const float*)d_in[2];
  const int*   pick  = (const int*)d_in[3];
  Wptrs wp;
  EvalP ep;
  for (int i = 0; i < 8; ++i) {
    wp.w[i] = (const float*)d_in[4 + 2*i];
    ep.b[i] = (const float*)d_in[5 + 2*i];
  }
  const float* w8 = (const float*)d_in[20];
  ep.b8 = (const float*)d_in[21];

  float* ws = (float*)d_ws;
  float* evalpts = ws;                 // 49152
  float* raw     = evalpts + 49152;    // 16384
  float* tminA   = raw + 16384;
  float* tmaxA   = tminA + 8192;
  float* nextS   = tmaxA + 8192;
  float* nextE   = nextS + 8192;
  float* accS    = nextE + 8192;
  float* accE    = accS + 8192;
  float* strack  = accE + 8192;        // 65536
  float* ptrack  = strack + 65536;     // 196608
  int*   mselS   = (int*)(ptrack + 196608);
  int*   mselE   = mselS + 8192;
  int*   mcarS   = mselE + 8192;
  int*   mcarE   = mcarS + 8192;
  float* w8c     = (float*)(mcarE + 8192);
  unsigned short* WTi = (unsigned short*)(w8c + 256);   // 983040 shorts interleaved
  ep.WTi = WTi; ep.w8c = w8c;
  float* out = (float*)d_out;

  prep_transpose<<<120, 256, 0, stream>>>(wp, WTi);
  prep_w8<<<1, 256, 0, stream>>>(w8, w8c);
  init_kernel<<<NR/256, 256, 0, stream>>>(ray0, rdir, tminA, tmaxA, evalpts, ptrack);
  eval_mfma<<<(2*NR)/32, 1024, 0, stream>>>(evalpts, raw, ep);
  for (int t = 0; t < 8; ++t) {
    march_kernel<<<NR/256, 256, 0, stream>>>(ray0, rdir, raw, nextS, nextE,
                                             mselS, mselE, mcarS, mcarE,
                                             accS, accE, tminA, tmaxA,
                                             strack, ptrack, evalpts, t);
    if (t < 7)
      eval_mfma<<<(2*NR)/32, 1024, 0, stream>>>(evalpts, raw, ep);
  }
  finalize_kernel<<<NR/256, 256, 0, stream>>>(ray0, rdir, frand, pick,
                                              strack, ptrack, accE, tminA, tmaxA, out);
}

// Round 21
// 583.643 us; speedup vs baseline: 1.7095x; 1.7095x over previous
//
#include <hip/hip_runtime.h>
#include <math.h>

#define NR 8192
#define NPICK 4096
#define SDF_THR_C 5e-5f

// output layout (floats)
#define OUT_DPRED 0
#define OUT_SDFL  8192
#define OUT_SAMP  16384
#define OUT_FIN   139264   // 16384 + 40960*3

typedef __attribute__((ext_vector_type(8))) short short8v;
typedef __attribute__((ext_vector_type(4))) float f32x4;

#define SK  320   // activation plane k-stride (shorts)
#define SKB 640   // bytes per plane row

struct Wptrs { const float* w[8]; };
struct EvalP {
  const float* b[8];
  const float* b8;
  const unsigned short* WTi;   // fragment-major: [g][ks][hi 512s | lo 512s]
  const float* w8c;
};

__device__ __forceinline__ unsigned short f2bf(float f) {
  unsigned int u = __float_as_uint(f);
  unsigned int r = u + 0x7FFFu + ((u >> 16) & 1u);
  return (unsigned short)(r >> 16);
}
__device__ __forceinline__ float bf2f(unsigned short h) {
  return __uint_as_float(((unsigned int)h) << 16);
}
// Fast softplus (validated round 9, absmax 0.0156). Embed trig stays EXACT
// sinf/cosf (the risky part of the round-4 failure).
__device__ __forceinline__ float softplus100(float h) {
  float z = 100.0f * h;
  return (fmaxf(z, 0.0f) + __logf(1.0f + __expf(-fabsf(z)))) * 0.01f;
}

// ---------------------------------------------------------------------------
// prep: transpose + bf16 hi/lo split, FRAGMENT-MAJOR layout:
// for col-group g=col>>4, ks=k>>5: the 64 MFMA lanes' 16-B fragments stored
// contiguously (hi 512 shorts, then lo 512). lane = lq*16 + lr, lq=(k>>3)&3,
// lr=col&15, e=k&7. A wave's bhv load = one coalesced 1 KB contiguous read
// (8 sequential lines) instead of 16 scattered K-major lines.
// ---------------------------------------------------------------------------
__global__ void prep_transpose(Wptrs wp, unsigned short* __restrict__ WTi)
{
  __shared__ unsigned short sh[64 * 66];
  __shared__ unsigned short sl[64 * 66];
  const int Kreal[8] = {39,256,256,256,295,256,256,256};
  const int Kp[8]    = {64,256,256,256,320,256,256,256};
  const int WB[8]    = {0,16384,81920,147456,212992,294912,360448,425984};
  const int cum[9]   = {0,4,20,36,52,72,88,104,120};
  int b = blockIdx.x;
  int l = 0;
  while (l < 7 && b >= cum[l + 1]) ++l;
  int tile = b - cum[l];
  int tk_n = Kp[l] >> 6;
  int tk = tile % tk_n, tc = tile / tk_n;
  const float* __restrict__ W = wp.w[l];
  int t = threadIdx.x;
  #pragma unroll
  for (int i = 0; i < 16; ++i) {
    int id = t + i * 256;
    int kl = id >> 6, cl = id & 63;
    int k = tk * 64 + kl, c = tc * 64 + cl;
    float v = (k < Kreal[l]) ? W[k * 256 + c] : 0.0f;
    unsigned short h = f2bf(v);
    unsigned short lo = f2bf(v - bf2f(h));
    sh[kl * 66 + cl] = h;
    sl[kl * 66 + cl] = lo;
  }
  __syncthreads();
  const int nksL = Kp[l] >> 5;
  #pragma unroll
  for (int i = 0; i < 16; ++i) {
    int id = t + i * 256;
    int cl = id >> 6, kl = id & 63;
    int col = tc * 64 + cl;
    int k = tk * 64 + kl;
    int g = col >> 4, lr = col & 15;
    int ksg = k >> 5, lq = (k >> 3) & 3, e = k & 7;
    int lane = lq * 16 + lr;
    size_t base = 2 * (size_t)WB[l] + ((size_t)(g * nksL + ksg)) * 1024 + lane * 8 + e;
    WTi[base]       = sh[kl * 66 + cl];
    WTi[base + 512] = sl[kl * 66 + cl];
  }
}

__global__ void prep_w8(const float* __restrict__ w8, float* __restrict__ w8c)
{
  int t = threadIdx.x;
  w8c[t] = w8[(size_t)t * 257];   // column 0 of (256,257)
}

// ---------------------------------------------------------------------------
// One layer, r17 tile (wave = 4 row-tiles x 1 col-tile), rotating 2-deep
// B-prefetch (r19), B reads from the fragment-major coalesced layout.
// Per-(row,col) MFMA chain identical to r17/r19 -> bit-identical outputs.
// ---------------------------------------------------------------------------
template<int NKS, int KPL>
__device__ __forceinline__ void layer_bpre(
    const unsigned short* __restrict__ wt, const float* __restrict__ bias,
    unsigned short* Ah, unsigned short* Al,
    int lq, int lr, int cw, int swA)
{
  const char* ahc = (const char*)Ah;
  const char* alc = (const char*)Al;
  f32x4 acc[4];
  #pragma unroll
  for (int i = 0; i < 4; ++i) acc[i] = (f32x4){0.f, 0.f, 0.f, 0.f};

  const int col = cw + lr;
  // fragment-major: group g = cw>>4, lane offset (lq*16+lr)*8 shorts
  const unsigned short* wcol = wt + (size_t)(cw >> 4) * NKS * 1024 + (lq * 16 + lr) * 8;

  short8v Bh[2], Bl[2];
  Bh[0] = *(const short8v*)(wcol);
  Bl[0] = *(const short8v*)(wcol + 512);

  #pragma unroll
  for (int ks = 0; ks < NKS; ++ks) {
    const int cur = ks & 1, nxt = cur ^ 1;
    if (ks + 1 < NKS) {
      const unsigned short* wn = wcol + (size_t)(ks + 1) * 1024;
      Bh[nxt] = *(const short8v*)(wn);
      Bl[nxt] = *(const short8v*)(wn + 512);
    }
    int ax = (ks * 64 + lq * 16) ^ swA;
    short8v ah[4], al[4];
    #pragma unroll
    for (int rt = 0; rt < 4; ++rt) {
      ah[rt] = *(const short8v*)(ahc + (rt * 16 + lr) * SKB + ax);
      al[rt] = *(const short8v*)(alc + (rt * 16 + lr) * SKB + ax);
    }
    #pragma unroll
    for (int rt = 0; rt < 4; ++rt) {
      acc[rt] = __builtin_amdgcn_mfma_f32_16x16x32_bf16(ah[rt], Bh[cur], acc[rt], 0, 0, 0);
      acc[rt] = __builtin_amdgcn_mfma_f32_16x16x32_bf16(al[rt], Bh[cur], acc[rt], 0, 0, 0);
      acc[rt] = __builtin_amdgcn_mfma_f32_16x16x32_bf16(ah[rt], Bl[cur], acc[rt], 0, 0, 0);
    }
  }

  __syncthreads();   // all plane reads of this layer complete

  char* ahw = (char*)Ah;
  char* alw = (char*)Al;
  {
    float bv = bias[col];
    int cb2 = col * 2;
    #pragma unroll
    for (int rt = 0; rt < 4; ++rt) {
      #pragma unroll
      for (int r = 0; r < 4; ++r) {
        float h = softplus100(acc[rt][r] + bv);
        unsigned short hh = f2bf(h);
        unsigned short hl = f2bf(h - bf2f(hh));
        int row = rt * 16 + lq * 4 + r;
        int addr = row * SKB + (cb2 ^ ((row & 7) << 4));
        *(unsigned short*)(ahw + addr) = hh;
        *(unsigned short*)(alw + addr) = hl;
      }
    }
  }
  __syncthreads();
}

// ---------------------------------------------------------------------------
// Fused 9-layer MLP via bf16x3 MFMA. pts (M x 3) -> sdf (M).
// 64 rows/block, 1024 threads (16 waves x 16 cols, acc[4]) — the r17/r19
// config (best: eval ~104-106 us) + coalesced fragment-major B.
// ---------------------------------------------------------------------------
__global__ __launch_bounds__(1024, 1)
void eval_mfma(const float* __restrict__ pts, float* __restrict__ sdf_out, EvalP P)
{
  __shared__ __align__(16) unsigned short Ah[64 * SK];   // 40 KB
  __shared__ __align__(16) unsigned short Al[64 * SK];   // 40 KB
  __shared__ float enc[64 * 40];                         // 10 KB
  __shared__ float red[8 * 64];                          // 2 KB
  const int WBA[8] = {0,16384,81920,147456,212992,294912,360448,425984};

  const int t = threadIdx.x;
  const int rbase = blockIdx.x * 64;

  // ---- embed: one thread per row -> enc[row][0..38] (EXACT sinf/cosf)
  if (t < 64) {
    const int r = rbase + t;
    float x = pts[3*r+0], y = pts[3*r+1], z = pts[3*r+2];
    float xn = ((x + 1.0f) * 0.5f) * 2.0f - 1.0f;
    float yn = ((y + 1.0f) * 0.5f) * 2.0f - 1.0f;
    float zn = ((z + 1.0f) * 0.5f) * 2.0f - 1.0f;
    float* row = enc + t * 40;
    row[0] = xn; row[1] = yn; row[2] = zn;
    float f = 1.0f;
    for (int lf = 0; lf < 6; ++lf) {
      float ax = xn * f, ay = yn * f, az = zn * f;
      row[3  + lf*3 + 0] = sinf(ax);
      row[3  + lf*3 + 1] = sinf(ay);
      row[3  + lf*3 + 2] = sinf(az);
      row[21 + lf*3 + 0] = cosf(ax);
      row[21 + lf*3 + 1] = cosf(ay);
      row[21 + lf*3 + 2] = cosf(az);
      f *= 2.0f;
    }
  }
  __syncthreads();

  // ---- scatter enc (bf16 hi/lo) to planes: k in [0,64) for L0, [256,320) for L4
  {
    char* ahp = (char*)Ah;
    char* alp = (char*)Al;
    int row = t >> 4, c4 = t & 15;   // 64 rows x 16 chunks of 4 k
    int sw = (row & 7) << 4;
    #pragma unroll
    for (int reg = 0; reg < 2; ++reg) {
      int koff = reg ? 256 : 0;
      #pragma unroll
      for (int e = 0; e < 4; e += 2) {
        int kl = c4 * 4 + e;
        float v0 = (kl     < 39) ? enc[row * 40 + kl]     : 0.0f;
        float v1 = (kl + 1 < 39) ? enc[row * 40 + kl + 1] : 0.0f;
        unsigned short h0 = f2bf(v0), h1 = f2bf(v1);
        unsigned short q0 = f2bf(v0 - bf2f(h0)), q1 = f2bf(v1 - bf2f(h1));
        int addr = row * SKB + (((koff + kl) * 2) ^ sw);
        *(unsigned int*)(ahp + addr) = (unsigned)h0 | ((unsigned)h1 << 16);
        *(unsigned int*)(alp + addr) = (unsigned)q0 | ((unsigned)q1 << 16);
      }
    }
  }
  __syncthreads();

  const int lane = t & 63, wv = t >> 6;   // 16 waves
  const int lq = lane >> 4, lr = lane & 15;
  const int cw = wv * 16;                 // wave owns 16 cols
  const char* ahc = (const char*)Ah;
  const int swA = (lr & 7) << 4;

  // ---- layers 0..7
  layer_bpre<2, 64>(P.WTi + 2 * (size_t)WBA[0], P.b[0], Ah, Al, lq, lr, cw, swA);
  #pragma unroll 1
  for (int l = 1; l < 8; ++l) {
    if (l == 4)
      layer_bpre<10, 320>(P.WTi + 2 * (size_t)WBA[4], P.b[4], Ah, Al, lq, lr, cw, swA);
    else
      layer_bpre<8, 256>(P.WTi + 2 * (size_t)WBA[l], P.b[l], Ah, Al, lq, lr, cw, swA);
  }

  // ---- layer 8: column 0 only; same 8x32-k partition + reduce order as r14.
  // threads 0-511: row = t&63, part = t>>6 (8 parts x 32 k, identical grouping).
  {
    const char* alc = (const char*)Al;
    if (t < 512) {
      int row = t & 63, part = t >> 6;
      int sw = (row & 7) << 4;
      float s = 0.0f;
      #pragma unroll
      for (int c = 0; c < 4; ++c) {
        int k = part * 32 + c * 8;
        int addr = row * SKB + ((k * 2) ^ sw);
        short8v vh = *(const short8v*)(ahc + addr);
        short8v vl = *(const short8v*)(alc + addr);
        #pragma unroll
        for (int e = 0; e < 8; ++e) {
          float h = bf2f((unsigned short)vh[e]) + bf2f((unsigned short)vl[e]);
          s = fmaf(h, P.w8c[k + e], s);
        }
      }
      red[part * 64 + row] = s;
    }
    __syncthreads();
    if (t < 64) {
      float tot = P.b8[0];
      #pragma unroll
      for (int p = 0; p < 8; ++p) tot += red[p * 64 + t];
      sdf_out[rbase + t] = tot;
    }
  }
}

// ---------------------------------------------------------------------------
// init: ray-AABB, initial points
// ---------------------------------------------------------------------------
__global__ void init_kernel(const float* __restrict__ ray0, const float* __restrict__ rdir,
                            float* tminA, float* tmaxA, float* evalpts, float* ptrack)
{
  int r = blockIdx.x * 256 + threadIdx.x;
  if (r >= NR) return;
  float ox = ray0[3*r], oy = ray0[3*r+1], oz = ray0[3*r+2];
  float dx = rdir[3*r], dy = rdir[3*r+1], dz = rdir[3*r+2];
  float ix = 1.0f/dx, iy = 1.0f/dy, iz = 1.0f/dz;
  float t1x = (-1.0f - ox)*ix, t2x = (1.0f - ox)*ix;
  float t1y = (-1.0f - oy)*iy, t2y = (1.0f - oy)*iy;
  float t1z = (-1.0f - oz)*iz, t2z = (1.0f - oz)*iz;
  float tmn = fmaxf(fmaxf(fminf(t1x,t2x), fminf(t1y,t2y)), fminf(t1z,t2z));
  float tmx = fminf(fminf(fmaxf(t1x,t2x), fmaxf(t1y,t2y)), fmaxf(t1z,t2z));
  tmn = fmaxf(tmn, 0.0f);
  tminA[r] = tmn; tmaxA[r] = tmx;
  float px = ox + tmn*dx, py = oy + tmn*dy, pz = oz + tmn*dz;
  float qx = ox + tmx*dx, qy = oy + tmx*dy, qz = oz + tmx*dz;
  evalpts[3*r+0] = px; evalpts[3*r+1] = py; evalpts[3*r+2] = pz;
  evalpts[3*(NR+r)+0] = qx; evalpts[3*(NR+r)+1] = qy; evalpts[3*(NR+r)+2] = qz;
  ptrack[r*24+0] = px; ptrack[r*24+1] = py; ptrack[r*24+2] = pz;
}

// ---------------------------------------------------------------------------
// march step t
// ---------------------------------------------------------------------------
__global__ void march_kernel(const float* __restrict__ ray0, const float* __restrict__ rdir,
                             const float* __restrict__ raw,
                             float* next_s, float* next_e,
                             int* msel_s, int* msel_e, int* mcar_s, int* mcar_e,
                             float* accS, float* accE,
                             const float* __restrict__ tminA, const float* __restrict__ tmaxA,
                             float* strack, float* ptrack, float* evalpts, int tstep)
{
  int r = blockIdx.x * 256 + threadIdx.x;
  if (r >= NR) return;
  float tmn = tminA[r], tmx = tmaxA[r];
  float rs = raw[r], re = raw[NR + r];
  float ns, ne, as_, ae; int ms, me;
  if (tstep == 0) {
    ns = rs; ne = re; ms = 1; me = 1; as_ = tmn; ae = tmx;
    strack[r*8 + 0] = rs;
  } else {
    ns = next_s[r]; ne = next_e[r];
    ns = msel_s[r] ? rs : ns;        // selection deferred from end of step t-1
    ne = msel_e[r] ? re : ne;
    strack[r*8 + tstep] = rs;        // sdf_tracks[:, t] = unmasked s-eval
    ms = mcar_s[r]; me = mcar_e[r];
    as_ = accS[r]; ae = accE[r];
  }
  float cs = (fabsf(ns) <= SDF_THR_C) ? 0.0f : ns;
  float ce = (fabsf(ne) <= SDF_THR_C) ? 0.0f : ne;
  ms = ms & ((fabsf(cs) > SDF_THR_C) ? 1 : 0);
  me = me & ((fabsf(ce) > SDF_THR_C) ? 1 : 0);
  as_ = fminf(as_ + cs, tmx);
  ae  = fminf(ae + ce, tmx);
  if (tstep < 7) {
    float ox = ray0[3*r], oy = ray0[3*r+1], oz = ray0[3*r+2];
    float dx = rdir[3*r], dy = rdir[3*r+1], dz = rdir[3*r+2];
    float px = ox + as_*dx, py = oy + as_*dy, pz = oz + as_*dz;
    float qx = ox + ae*dx,  qy = oy + ae*dy,  qz = oz + ae*dz;
    ptrack[r*24 + (tstep+1)*3 + 0] = px;
    ptrack[r*24 + (tstep+1)*3 + 1] = py;
    ptrack[r*24 + (tstep+1)*3 + 2] = pz;
    evalpts[3*r+0] = px; evalpts[3*r+1] = py; evalpts[3*r+2] = pz;
    evalpts[3*(NR+r)+0] = qx; evalpts[3*(NR+r)+1] = qy; evalpts[3*(NR+r)+2] = qz;
  }
  int ok = (as_ < ae) ? 1 : 0;
  msel_s[r] = ms;       msel_e[r] = me;        // pre-ok masks: used for next select
  mcar_s[r] = ms & ok;  mcar_e[r] = me & ok;   // carry masks
  next_s[r] = ns; next_e[r] = ne;
  accS[r] = as_; accE[r] = ae;
}

// ---------------------------------------------------------------------------
// finalize: outputs
// ---------------------------------------------------------------------------
__global__ void finalize_kernel(const float* __restrict__ ray0, const float* __restrict__ rdir,
                                const float* __restrict__ frand, const int* __restrict__ pick,
                                const float* __restrict__ strack, const float* __restrict__ ptrack,
                                const float* __restrict__ accE,
                                const float* __restrict__ tminA, const float* __restrict__ tmaxA,
                                float* __restrict__ out)
{
  int r = blockIdx.x * 256 + threadIdx.x;
  if (r < NR) {
    float tmn = tminA[r], tmx = tmaxA[r];
    float sum = 0.f;
    #pragma unroll
    for (int tt = 0; tt < 8; ++tt) sum += strack[r*8 + tt];
    out[OUT_DPRED + r] = fminf(sum + tmn, tmx);
    float last = strack[r*8 + 7];
    out[OUT_SDFL + r] = last;
    out[OUT_FIN + r] = (fabsf(last) < 0.0015625f) ? 1.0f : 0.0f;
    float du = fminf(1.5f * accE[r], tmx);
    float fr = frand[r];
    float dsm = (1.0f - fr) * du + fr * tmn;
    float ox = ray0[3*r], oy = ray0[3*r+1], oz = ray0[3*r+2];
    float dx = rdir[3*r], dy = rdir[3*r+1], dz = rdir[3*r+2];
    int o2 = OUT_SAMP + 98304 + 3*r;
    out[o2+0] = ox + dsm*dx;
    out[o2+1] = oy + dsm*dy;
    out[o2+2] = oz + dsm*dz;
  }
  if (r < NPICK) {
    int ray = pick[r];
    #pragma unroll
    for (int i = 0; i < 24; ++i)
      out[OUT_SAMP + r*24 + i] = ptrack[ray*24 + i];
  }
}

// ---------------------------------------------------------------------------
extern "C" void kernel_launch(void* const* d_in, const int* in_sizes, int n_in,
                              void* d_out, int out_size, void* d_ws, size_t ws_size,
                              hipStream_t stream)
{
  const float* ray0  = (const float*)d_in[0];
  const float* rdir  = (const float*)d_in[1];
  const float* frand = (const float*)d_in[2];
  const int*   pick  = (const int*)d_in[3];
  Wptrs wp;
  EvalP ep;
  for (int i = 0; i < 8; ++i) {
    wp.w[i] = (const float*)d_in[4 + 2*i];
    ep.b[i] = (const float*)d_in[5 + 2*i];
  }
  const float* w8 = (const float*)d_in[20];
  ep.b8 = (const float*)d_in[21];

  float* ws = (float*)d_ws;
  float* evalpts = ws;                 // 49152
  float* raw     = evalpts + 49152;    // 16384
  float* tminA   = raw + 16384;
  float* tmaxA   = tminA + 8192;
  float* nextS   = tmaxA + 8192;
  float* nextE   = nextS + 8192;
  float* accS    = nextE + 8192;
  float* accE    = accS + 8192;
  float* strack  = accE + 8192;        // 65536
  float* ptrack  = strack + 65536;     // 196608
  int*   mselS   = (int*)(ptrack + 196608);
  int*   mselE   = mselS + 8192;
  int*   mcarS   = mselE + 8192;
  int*   mcarE   = mcarS + 8192;
  float* w8c     = (float*)(mcarE + 8192);
  unsigned short* WTi = (unsigned short*)(w8c + 256);   // 983040 shorts fragment-major
  ep.WTi = WTi; ep.w8c = w8c;
  float* out = (float*)d_out;

  prep_transpose<<<120, 256, 0, stream>>>(wp, WTi);
  prep_w8<<<1, 256, 0, stream>>>(w8, w8c);
  init_kernel<<<NR/256, 256, 0, stream>>>(ray0, rdir, tminA, tmaxA, evalpts, ptrack);
  eval_mfma<<<(2*NR)/64, 1024, 0, stream>>>(evalpts, raw, ep);
  for (int t = 0; t < 8; ++t) {
    march_kernel<<<NR/256, 256, 0, stream>>>(ray0, rdir, raw, nextS, nextE,
                                             mselS, mselE, mcarS, mcarE,
                                             accS, accE, tminA, tmaxA,
                                             strack, ptrack, evalpts, t);
    if (t < 7)
      eval_mfma<<<(2*NR)/64, 1024, 0, stream>>>(evalpts, raw, ep);
  }
  finalize_kernel<<<NR/256, 256, 0, stream>>>(ray0, rdir, frand, pick,
                                              strack, ptrack, accE, tminA, tmaxA, out);
}

// Round 22
// 542.854 us; speedup vs baseline: 1.8380x; 1.0751x over previous
//
#include <hip/hip_runtime.h>
#include <math.h>

#define NR 8192
#define NPICK 4096
#define SDF_THR_C 5e-5f

// output layout (floats)
#define OUT_DPRED 0
#define OUT_SDFL  8192
#define OUT_SAMP  16384
#define OUT_FIN   139264   // 16384 + 40960*3

typedef __attribute__((ext_vector_type(8))) short short8v;
typedef __attribute__((ext_vector_type(4))) float f32x4;

#define SK  320   // activation plane k-stride (shorts)
#define SKB 640   // bytes per plane row

struct Wptrs { const float* w[8]; };
struct EvalP {
  const float* b[8];
  const float* b8;
  const unsigned short* WTi;   // fragment-major: [g][ks][hi 512s | lo 512s]
  const float* w8c;
  const float* ray0; const float* rdir;
  float* tminA; float* tmaxA;
  float* nextS; float* nextE;
  int* mselS; int* mselE; int* mcarS; int* mcarE;
  float* accS; float* accE;
  float* strack; float* ptrack; float* evalpts;
};

__device__ __forceinline__ unsigned short f2bf(float f) {
  unsigned int u = __float_as_uint(f);
  unsigned int r = u + 0x7FFFu + ((u >> 16) & 1u);
  return (unsigned short)(r >> 16);
}
__device__ __forceinline__ float bf2f(unsigned short h) {
  return __uint_as_float(((unsigned int)h) << 16);
}
// Fast softplus (validated round 9, absmax 0.0156). Embed trig stays EXACT
// sinf/cosf (the risky part of the round-4 failure).
__device__ __forceinline__ float softplus100(float h) {
  float z = 100.0f * h;
  return (fmaxf(z, 0.0f) + __logf(1.0f + __expf(-fabsf(z)))) * 0.01f;
}

// ---------------------------------------------------------------------------
// prep: transpose + bf16 hi/lo split, FRAGMENT-MAJOR layout (r21 — the big
// win): for col-group g=col>>4, ks=k>>5 the 64 lanes' 16-B fragments are
// contiguous (hi 512 shorts then lo 512) -> wave B-load = 1 KB coalesced.
// ---------------------------------------------------------------------------
__global__ void prep_transpose(Wptrs wp, unsigned short* __restrict__ WTi)
{
  __shared__ unsigned short sh[64 * 66];
  __shared__ unsigned short sl[64 * 66];
  const int Kreal[8] = {39,256,256,256,295,256,256,256};
  const int Kp[8]    = {64,256,256,256,320,256,256,256};
  const int WB[8]    = {0,16384,81920,147456,212992,294912,360448,425984};
  const int cum[9]   = {0,4,20,36,52,72,88,104,120};
  int b = blockIdx.x;
  int l = 0;
  while (l < 7 && b >= cum[l + 1]) ++l;
  int tile = b - cum[l];
  int tk_n = Kp[l] >> 6;
  int tk = tile % tk_n, tc = tile / tk_n;
  const float* __restrict__ W = wp.w[l];
  int t = threadIdx.x;
  #pragma unroll
  for (int i = 0; i < 16; ++i) {
    int id = t + i * 256;
    int kl = id >> 6, cl = id & 63;
    int k = tk * 64 + kl, c = tc * 64 + cl;
    float v = (k < Kreal[l]) ? W[k * 256 + c] : 0.0f;
    unsigned short h = f2bf(v);
    unsigned short lo = f2bf(v - bf2f(h));
    sh[kl * 66 + cl] = h;
    sl[kl * 66 + cl] = lo;
  }
  __syncthreads();
  const int nksL = Kp[l] >> 5;
  #pragma unroll
  for (int i = 0; i < 16; ++i) {
    int id = t + i * 256;
    int cl = id >> 6, kl = id & 63;
    int col = tc * 64 + cl;
    int k = tk * 64 + kl;
    int g = col >> 4, lr = col & 15;
    int ksg = k >> 5, lq = (k >> 3) & 3, e = k & 7;
    int lane = lq * 16 + lr;
    size_t base = 2 * (size_t)WB[l] + ((size_t)(g * nksL + ksg)) * 1024 + lane * 8 + e;
    WTi[base]       = sh[kl * 66 + cl];
    WTi[base + 512] = sl[kl * 66 + cl];
  }
}

__global__ void prep_w8(const float* __restrict__ w8, float* __restrict__ w8c)
{
  int t = threadIdx.x;
  w8c[t] = w8[(size_t)t * 257];   // column 0 of (256,257)
}

// ---------------------------------------------------------------------------
// One layer, r17 tile (wave = 4 row-tiles x 1 col-tile), rotating 2-deep
// B-prefetch, fragment-major coalesced B (r21 core — unchanged).
// ---------------------------------------------------------------------------
template<int NKS, int KPL>
__device__ __forceinline__ void layer_bpre(
    const unsigned short* __restrict__ wt, const float* __restrict__ bias,
    unsigned short* Ah, unsigned short* Al,
    int lq, int lr, int cw, int swA)
{
  const char* ahc = (const char*)Ah;
  const char* alc = (const char*)Al;
  f32x4 acc[4];
  #pragma unroll
  for (int i = 0; i < 4; ++i) acc[i] = (f32x4){0.f, 0.f, 0.f, 0.f};

  const int col = cw + lr;
  const unsigned short* wcol = wt + (size_t)(cw >> 4) * NKS * 1024 + (lq * 16 + lr) * 8;

  short8v Bh[2], Bl[2];
  Bh[0] = *(const short8v*)(wcol);
  Bl[0] = *(const short8v*)(wcol + 512);

  #pragma unroll
  for (int ks = 0; ks < NKS; ++ks) {
    const int cur = ks & 1, nxt = cur ^ 1;
    if (ks + 1 < NKS) {
      const unsigned short* wn = wcol + (size_t)(ks + 1) * 1024;
      Bh[nxt] = *(const short8v*)(wn);
      Bl[nxt] = *(const short8v*)(wn + 512);
    }
    int ax = (ks * 64 + lq * 16) ^ swA;
    short8v ah[4], al[4];
    #pragma unroll
    for (int rt = 0; rt < 4; ++rt) {
      ah[rt] = *(const short8v*)(ahc + (rt * 16 + lr) * SKB + ax);
      al[rt] = *(const short8v*)(alc + (rt * 16 + lr) * SKB + ax);
    }
    #pragma unroll
    for (int rt = 0; rt < 4; ++rt) {
      acc[rt] = __builtin_amdgcn_mfma_f32_16x16x32_bf16(ah[rt], Bh[cur], acc[rt], 0, 0, 0);
      acc[rt] = __builtin_amdgcn_mfma_f32_16x16x32_bf16(al[rt], Bh[cur], acc[rt], 0, 0, 0);
      acc[rt] = __builtin_amdgcn_mfma_f32_16x16x32_bf16(ah[rt], Bl[cur], acc[rt], 0, 0, 0);
    }
  }

  __syncthreads();   // all plane reads of this layer complete

  char* ahw = (char*)Ah;
  char* alw = (char*)Al;
  {
    float bv = bias[col];
    int cb2 = col * 2;
    #pragma unroll
    for (int rt = 0; rt < 4; ++rt) {
      #pragma unroll
      for (int r = 0; r < 4; ++r) {
        float h = softplus100(acc[rt][r] + bv);
        unsigned short hh = f2bf(h);
        unsigned short hl = f2bf(h - bf2f(hh));
        int row = rt * 16 + lq * 4 + r;
        int addr = row * SKB + (cb2 ^ ((row & 7) << 4));
        *(unsigned short*)(ahw + addr) = hh;
        *(unsigned short*)(alw + addr) = hl;
      }
    }
  }
  __syncthreads();
}

// ---------------------------------------------------------------------------
// Fused eval+march. 64 rows = 32 rays/block: rows 0-31 = s-points, rows
// 32-63 = e-points. r21 eval core verbatim; march body (verbatim) runs on
// threads 0-31 at the tail -> 8 march launches eliminated. Embed parallel
// (r10 pattern, bit-identical values).
// ---------------------------------------------------------------------------
__global__ __launch_bounds__(1024, 1)
void eval_fused(EvalP P, int tstep)
{
  __shared__ __align__(16) unsigned short Ah[64 * SK];   // 40 KB
  __shared__ __align__(16) unsigned short Al[64 * SK];   // 40 KB
  __shared__ float enc[64 * 40];                         // 10 KB
  __shared__ float red[8 * 64];                          // 2 KB
  __shared__ float sdfv[64];
  const int WBA[8] = {0,16384,81920,147456,212992,294912,360448,425984};

  const int t = threadIdx.x;
  const int rayb = blockIdx.x * 32;

  // ---- embed part 1: normalized coords (192 threads, 64 rows x 3)
  if (t < 192) {
    int row = t / 3, c = t - row * 3;
    int idx = (row < 32) ? (rayb + row) : (NR + rayb + row - 32);
    float p = P.evalpts[3 * idx + c];
    enc[row * 40 + c] = ((p + 1.0f) * 0.5f) * 2.0f - 1.0f;
  }
  __syncthreads();
  // ---- embed part 2: 64 rows x 36 trig over all 1024 threads (exact
  // sinf/cosf; arg = xn * 2^lf — identical product to the serial version)
  for (int i = t; i < 64 * 36; i += 1024) {
    int row = i / 36, j = i - row * 36;
    int jj = (j < 18) ? j : j - 18;
    int c = jj % 3, lf = jj / 3;
    float arg = enc[row * 40 + c] * (float)(1 << lf);
    enc[row * 40 + 3 + j] = (j < 18) ? sinf(arg) : cosf(arg);
  }
  __syncthreads();

  // ---- scatter enc (bf16 hi/lo) to planes: k in [0,64) and [256,320)
  {
    char* ahp = (char*)Ah;
    char* alp = (char*)Al;
    int row = t >> 4, c4 = t & 15;   // 64 rows x 16 chunks of 4 k
    int sw = (row & 7) << 4;
    #pragma unroll
    for (int reg = 0; reg < 2; ++reg) {
      int koff = reg ? 256 : 0;
      #pragma unroll
      for (int e = 0; e < 4; e += 2) {
        int kl = c4 * 4 + e;
        float v0 = (kl     < 39) ? enc[row * 40 + kl]     : 0.0f;
        float v1 = (kl + 1 < 39) ? enc[row * 40 + kl + 1] : 0.0f;
        unsigned short h0 = f2bf(v0), h1 = f2bf(v1);
        unsigned short q0 = f2bf(v0 - bf2f(h0)), q1 = f2bf(v1 - bf2f(h1));
        int addr = row * SKB + (((koff + kl) * 2) ^ sw);
        *(unsigned int*)(ahp + addr) = (unsigned)h0 | ((unsigned)h1 << 16);
        *(unsigned int*)(alp + addr) = (unsigned)q0 | ((unsigned)q1 << 16);
      }
    }
  }
  __syncthreads();

  const int lane = t & 63, wv = t >> 6;   // 16 waves
  const int lq = lane >> 4, lr = lane & 15;
  const int cw = wv * 16;                 // wave owns 16 cols
  const char* ahc = (const char*)Ah;
  const int swA = (lr & 7) << 4;

  // ---- layers 0..7
  layer_bpre<2, 64>(P.WTi + 2 * (size_t)WBA[0], P.b[0], Ah, Al, lq, lr, cw, swA);
  #pragma unroll 1
  for (int l = 1; l < 8; ++l) {
    if (l == 4)
      layer_bpre<10, 320>(P.WTi + 2 * (size_t)WBA[4], P.b[4], Ah, Al, lq, lr, cw, swA);
    else
      layer_bpre<8, 256>(P.WTi + 2 * (size_t)WBA[l], P.b[l], Ah, Al, lq, lr, cw, swA);
  }

  // ---- layer 8: column 0 only; 8x32-k partition + part-ascending reduce
  {
    const char* alc = (const char*)Al;
    if (t < 512) {
      int row = t & 63, part = t >> 6;
      int sw = (row & 7) << 4;
      float s = 0.0f;
      #pragma unroll
      for (int c = 0; c < 4; ++c) {
        int k = part * 32 + c * 8;
        int addr = row * SKB + ((k * 2) ^ sw);
        short8v vh = *(const short8v*)(ahc + addr);
        short8v vl = *(const short8v*)(alc + addr);
        #pragma unroll
        for (int e = 0; e < 8; ++e) {
          float h = bf2f((unsigned short)vh[e]) + bf2f((unsigned short)vl[e]);
          s = fmaf(h, P.w8c[k + e], s);
        }
      }
      red[part * 64 + row] = s;
    }
    __syncthreads();
    if (t < 64) {
      float tot = P.b8[0];
      #pragma unroll
      for (int p = 0; p < 8; ++p) tot += red[p * 64 + t];
      sdfv[t] = tot;
    }
    __syncthreads();
  }

  // ---- march tail (march_kernel body verbatim; threads 0-31)
  if (t < 32) {
    int r = rayb + t;
    float tmn = P.tminA[r], tmx = P.tmaxA[r];
    float rs = sdfv[t], re = sdfv[32 + t];
    float ns, ne, as_, ae; int ms, me;
    if (tstep == 0) {
      ns = rs; ne = re; ms = 1; me = 1; as_ = tmn; ae = tmx;
    } else {
      ns = P.nextS[r]; ne = P.nextE[r];
      ns = P.mselS[r] ? rs : ns;       // selection deferred from step t-1
      ne = P.mselE[r] ? re : ne;
      ms = P.mcarS[r]; me = P.mcarE[r];
      as_ = P.accS[r]; ae = P.accE[r];
    }
    P.strack[r*8 + tstep] = rs;        // sdf_tracks[:, t] = unmasked s-eval
    float cs = (fabsf(ns) <= SDF_THR_C) ? 0.0f : ns;
    float ce = (fabsf(ne) <= SDF_THR_C) ? 0.0f : ne;
    ms = ms & ((fabsf(cs) > SDF_THR_C) ? 1 : 0);
    me = me & ((fabsf(ce) > SDF_THR_C) ? 1 : 0);
    as_ = fminf(as_ + cs, tmx);
    ae  = fminf(ae + ce, tmx);
    if (tstep < 7) {
      float ox = P.ray0[3*r], oy = P.ray0[3*r+1], oz = P.ray0[3*r+2];
      float dx = P.rdir[3*r], dy = P.rdir[3*r+1], dz = P.rdir[3*r+2];
      float px = ox + as_*dx, py = oy + as_*dy, pz = oz + as_*dz;
      float qx = ox + ae*dx,  qy = oy + ae*dy,  qz = oz + ae*dz;
      P.ptrack[r*24 + (tstep+1)*3 + 0] = px;
      P.ptrack[r*24 + (tstep+1)*3 + 1] = py;
      P.ptrack[r*24 + (tstep+1)*3 + 2] = pz;
      P.evalpts[3*r+0] = px; P.evalpts[3*r+1] = py; P.evalpts[3*r+2] = pz;
      P.evalpts[3*(NR+r)+0] = qx; P.evalpts[3*(NR+r)+1] = qy; P.evalpts[3*(NR+r)+2] = qz;
    }
    int ok = (as_ < ae) ? 1 : 0;
    P.mselS[r] = ms;       P.mselE[r] = me;       // pre-ok (select) masks
    P.mcarS[r] = ms & ok;  P.mcarE[r] = me & ok;  // carry masks
    P.nextS[r] = ns; P.nextE[r] = ne;
    P.accS[r] = as_; P.accE[r] = ae;
  }
}

// ---------------------------------------------------------------------------
// init: ray-AABB, initial points
// ---------------------------------------------------------------------------
__global__ void init_kernel(const float* __restrict__ ray0, const float* __restrict__ rdir,
                            float* tminA, float* tmaxA, float* evalpts, float* ptrack)
{
  int r = blockIdx.x * 256 + threadIdx.x;
  if (r >= NR) return;
  float ox = ray0[3*r], oy = ray0[3*r+1], oz = ray0[3*r+2];
  float dx = rdir[3*r], dy = rdir[3*r+1], dz = rdir[3*r+2];
  float ix = 1.0f/dx, iy = 1.0f/dy, iz = 1.0f/dz;
  float t1x = (-1.0f - ox)*ix, t2x = (1.0f - ox)*ix;
  float t1y = (-1.0f - oy)*iy, t2y = (1.0f - oy)*iy;
  float t1z = (-1.0f - oz)*iz, t2z = (1.0f - oz)*iz;
  float tmn = fmaxf(fmaxf(fminf(t1x,t2x), fminf(t1y,t2y)), fminf(t1z,t2z));
  float tmx = fminf(fminf(fmaxf(t1x,t2x), fmaxf(t1y,t2y)), fmaxf(t1z,t2z));
  tmn = fmaxf(tmn, 0.0f);
  tminA[r] = tmn; tmaxA[r] = tmx;
  float px = ox + tmn*dx, py = oy + tmn*dy, pz = oz + tmn*dz;
  float qx = ox + tmx*dx, qy = oy + tmx*dy, qz = oz + tmx*dz;
  evalpts[3*r+0] = px; evalpts[3*r+1] = py; evalpts[3*r+2] = pz;
  evalpts[3*(NR+r)+0] = qx; evalpts[3*(NR+r)+1] = qy; evalpts[3*(NR+r)+2] = qz;
  ptrack[r*24+0] = px; ptrack[r*24+1] = py; ptrack[r*24+2] = pz;
}

// ---------------------------------------------------------------------------
// finalize: outputs
// ---------------------------------------------------------------------------
__global__ void finalize_kernel(const float* __restrict__ ray0, const float* __restrict__ rdir,
                                const float* __restrict__ frand, const int* __restrict__ pick,
                                const float* __restrict__ strack, const float* __restrict__ ptrack,
                                const float* __restrict__ accE,
                                const float* __restrict__ tminA, const float* __restrict__ tmaxA,
                                float* __restrict__ out)
{
  int r = blockIdx.x * 256 + threadIdx.x;
  if (r < NR) {
    float tmn = tminA[r], tmx = tmaxA[r];
    float sum = 0.f;
    #pragma unroll
    for (int tt = 0; tt < 8; ++tt) sum += strack[r*8 + tt];
    out[OUT_DPRED + r] = fminf(sum + tmn, tmx);
    float last = strack[r*8 + 7];
    out[OUT_SDFL + r] = last;
    out[OUT_FIN + r] = (fabsf(last) < 0.0015625f) ? 1.0f : 0.0f;
    float du = fminf(1.5f * accE[r], tmx);
    float fr = frand[r];
    float dsm = (1.0f - fr) * du + fr * tmn;
    float ox = ray0[3*r], oy = ray0[3*r+1], oz = ray0[3*r+2];
    float dx = rdir[3*r], dy = rdir[3*r+1], dz = rdir[3*r+2];
    int o2 = OUT_SAMP + 98304 + 3*r;
    out[o2+0] = ox + dsm*dx;
    out[o2+1] = oy + dsm*dy;
    out[o2+2] = oz + dsm*dz;
  }
  if (r < NPICK) {
    int ray = pick[r];
    #pragma unroll
    for (int i = 0; i < 24; ++i)
      out[OUT_SAMP + r*24 + i] = ptrack[ray*24 + i];
  }
}

// ---------------------------------------------------------------------------
extern "C" void kernel_launch(void* const* d_in, const int* in_sizes, int n_in,
                              void* d_out, int out_size, void* d_ws, size_t ws_size,
                              hipStream_t stream)
{
  const float* ray0  = (const float*)d_in[0];
  const float* rdir  = (const float*)d_in[1];
  const float* frand = (const float*)d_in[2];
  const int*   pick  = (const int*)d_in[3];
  Wptrs wp;
  EvalP ep;
  for (int i = 0; i < 8; ++i) {
    wp.w[i] = (const float*)d_in[4 + 2*i];
    ep.b[i] = (const float*)d_in[5 + 2*i];
  }
  const float* w8 = (const float*)d_in[20];
  ep.b8 = (const float*)d_in[21];
  ep.ray0 = ray0; ep.rdir = rdir;

  float* ws = (float*)d_ws;
  float* evalpts = ws;                 // 49152
  float* tminA   = evalpts + 49152;
  float* tmaxA   = tminA + 8192;
  float* nextS   = tmaxA + 8192;
  float* nextE   = nextS + 8192;
  float* accS    = nextE + 8192;
  float* accE    = accS + 8192;
  float* strack  = accE + 8192;        // 65536
  float* ptrack  = strack + 65536;     // 196608
  int*   mselS   = (int*)(ptrack + 196608);
  int*   mselE   = mselS + 8192;
  int*   mcarS   = mselE + 8192;
  int*   mcarE   = mcarS + 8192;
  float* w8c     = (float*)(mcarE + 8192);
  unsigned short* WTi = (unsigned short*)(w8c + 256);   // 983040 shorts fragment-major
  ep.WTi = WTi; ep.w8c = w8c;
  ep.tminA = tminA; ep.tmaxA = tmaxA;
  ep.nextS = nextS; ep.nextE = nextE;
  ep.mselS = mselS; ep.mselE = mselE; ep.mcarS = mcarS; ep.mcarE = mcarE;
  ep.accS = accS; ep.accE = accE;
  ep.strack = strack; ep.ptrack = ptrack; ep.evalpts = evalpts;
  float* out = (float*)d_out;

  prep_transpose<<<120, 256, 0, stream>>>(wp, WTi);
  prep_w8<<<1, 256, 0, stream>>>(w8, w8c);
  init_kernel<<<NR/256, 256, 0, stream>>>(ray0, rdir, tminA, tmaxA, evalpts, ptrack);
  for (int t = 0; t < 8; ++t)
    eval_fused<<<NR/32, 1024, 0, stream>>>(ep, t);
  finalize_kernel<<<NR/256, 256, 0, stream>>>(ray0, rdir, frand, pick,
                                              strack, ptrack, accE, tminA, tmaxA, out);
}